// Round 7
// baseline (503.904 us; speedup 1.0000x reference)
//
#include <hip/hip_runtime.h>

#define NROWS 262144   // 256*32*32
#define DDIM  64
#define KCODE 1024
#define GATHER_BLOCKS ((NROWS * 16) / 256)   // 16384
#define WINDOW 4e-3f   // certified: worst-case |approx_s - numpy_s| < 1.6e-3; 2.5x margin
#define FT 4           // tiles per staged chunk (32 KB/chunk: 4 tiles x 8 KB)
#define NCHUNK (KCODE / 32 / FT)   // 8

// ---- ws layout (bytes) ----
// [0)        eT       float[KCODE*DDIM]   = 262144 B  (codebook transposed, [k][d])
// [262144)   norms    float[KCODE]        = 4096 B    (numpy-order sum of squares)
// [266240)   ph       ushort[32*4*64*8]   = 131072 B  (bf16 hi, 32x32-fragment-packed)
// [397312)   pl       ushort[32*4*64*8]   = 131072 B  (bf16 lo, 32x32-fragment-packed)
// [528384)   idx      int[NROWS]          = 1 MiB     (bit31 = needs exact rescore)
// [1576960)  partials double[16384]       = 128 KiB
// [1708032)  cnt      int                 (compact-list counter, zeroed by vq_prep)
// [1709056)  list     int[NROWS]          = 1 MiB     (compacted flagged-row worklist)
//
// Fragment pack (32x32x16): ph/pl[((tile*4+kstep)<<9) + lane*8 + j] holds bf16
// hi/lo of dim d = kstep*16 + (lane>>5)*8 + j of code k = tile*32 + (lane&31) —
// the exact B lane-fragment of mfma_f32_32x32x16_bf16 (C layout HW-verified
// m74/m101). Loads/ds_reads are 64 lanes x contiguous 16 B.
//
// ROUND-7 RATIONALE (counter-derived): r6 halved MFMA instrs but DOUBLED
// per-wave pack traffic (8192 waves x 256 KB = 2.1 GB from L2; demand ~4x the
// 34.5 TB/s L2 ceiling -> 61 us floor + overlap loss = 146 us measured).
// r5's LDS staging was neutral THEN (regime was MFMA-count/occupancy-bound);
// NOW the regime is L2-BW-bound, so staging pays: 512-thread blocks stage the
// pack once per block (268 MB total, ~8 us), FT=4 dbuf = 68 KB LDS -> 2
// blocks/CU = 4 waves/SIMD (occupancy UP from 3). Floors: MFMA 41 us, VALU
// ~25 us, LDS ~27 us. Staged bytes identical -> math unchanged.
//
// SEMANTICS (verified bit-exact, absmax 0.0): oracle = numpy fp32,
// AVX512 pairwise sumsq, sequential-d fp32-FMA dot, dist = fl(fl(sumx+norm)-2dot),
// first-index argmin, out = fl(x + fl(q-x)). Exact path preserved in vq_prep /
// vq_rescore* / vq_gather. vq_filter is APPROXIMATE with a certified window;
// near-ties are rescored exactly. Split-product set unchanged (hh+hl+lh, fp32
// accum) -> error class unchanged, margin holds.
//
// HISTORY (counter-verified):
//  rescore: r0 305us latency -> r1 spill 626us BAD -> r2 348us serialized
//           -> r3 vq_rescore_b block-per-4-rows: off top-5 (<40us). GOOD.
//  filter:  r3 253us divergent-B -> r4 166us fragment-packed -> r5 167us LDS
//           staging NEUTRAL (wrong regime) -> r6 146us 32x32 MFMA + 4wv/SIMD
//           attempt (L2-BW-bound, 2.1 GB pack traffic).

typedef short bf16x8 __attribute__((ext_vector_type(8)));
typedef float f32x4  __attribute__((ext_vector_type(4)));
typedef float f32x16 __attribute__((ext_vector_type(16)));

__device__ __forceinline__ unsigned short bf16_rne(float f) {
    unsigned u = __float_as_uint(f);
    unsigned r = u + 0x7fffu + ((u >> 16) & 1u);
    return (unsigned short)(r >> 16);
}

// ------------------------------------------------------------------
// P: transpose codebook, numpy-order norms, 32x32-fragment-packed bf16 hi/lo,
// zero worklist cnt
__global__ __launch_bounds__(256) void vq_prep(const float* __restrict__ e,
                                               float* __restrict__ eT,
                                               float* __restrict__ norms,
                                               unsigned short* __restrict__ ph,
                                               unsigned short* __restrict__ pl,
                                               int* cnt) {
#pragma clang fp contract(off)
    if (cnt && blockIdx.x == 0 && threadIdx.x == 0) *cnt = 0;
    const int k = blockIdx.x * 256 + threadIdx.x;   // 4 blocks x 256 = 1024
    const int tile = k >> 5;          // 32 codes per 32x32 tile
    const int col  = k & 31;
    float acc = 0.0f;
    for (int d = 0; d < DDIM; ++d) {
        float v = e[d * KCODE + k];      // e is [D][K]; coalesced across k-lanes
        eT[(k << 6) + d] = v;
        unsigned short h = bf16_rne(v);
        float hf = __uint_as_float((unsigned)h << 16);
        // B-fragment pack: kstep = d>>4, lane = ((d&15)>>3)*32 + col, j = d&7
        const int kstep = d >> 4;
        const int lane  = (((d & 15) >> 3) << 5) | col;
        const int pidx  = (((tile << 2) + kstep) << 9) + (lane << 3) + (d & 7);
        ph[pidx] = h;
        pl[pidx] = bf16_rne(v - hf);     // Sterbenz: v-hf exact
        float sq = v * v;                // rounded square (numpy elementwise mul)
        acc = acc + sq;                  // sequential adds (numpy axis-0 reduce)
    }
    norms[k] = acc;
}

// ------------------------------------------------------------------
// numpy AVX512 pairwise sum of fl(x_d^2) — exact op order, do not touch
__device__ __forceinline__ float numpy_sumsq(const float* xr) {
#pragma clang fp contract(off)
    float u[16];
#pragma unroll
    for (int j = 0; j < 16; ++j) {
        float p0 = xr[j     ] * xr[j     ];
        float p1 = xr[j + 16] * xr[j + 16];
        float p2 = xr[j + 32] * xr[j + 32];
        float p3 = xr[j + 48] * xr[j + 48];
        u[j] = (p0 + p1) + (p2 + p3);
    }
    float v8[8];
#pragma unroll
    for (int j = 0; j < 8; ++j) v8[j] = u[j] + u[j + 8];
    float w4[4];
#pragma unroll
    for (int j = 0; j < 4; ++j) w4[j] = v8[j] + v8[j + 4];
    float y0 = w4[0] + w4[2];
    float y1 = w4[1] + w4[3];
    return y0 + y1;
}

// ------------------------------------------------------------------
// 1: 32x32x16-MFMA split-bf16 approximate argmin. Block = 8 waves x 32 rows.
// B fragments staged to LDS (FT=4 tile chunks, double-buffered, staged ONCE
// per block). Per k-tile per wave: 12 MFMAs (hh,hl,lh per kstep), 16 slots.
__global__ __launch_bounds__(512, 4) void vq_filter(const float* __restrict__ x,
                                                    const unsigned short* __restrict__ ph,
                                                    const unsigned short* __restrict__ pl,
                                                    const float* __restrict__ norms,
                                                    int* __restrict__ idx,
                                                    int* cnt,
                                                    int* list) {
    const int lane = threadIdx.x & 63;
    const int wave = threadIdx.x >> 6;              // 0..7
    const int wrow = blockIdx.x * 256 + wave * 32;  // 32 rows per wave
    const int arow = lane & 31;       // A row / C col-class
    const int half = lane >> 5;       // A k-group / C row-half

    // [buf][ti*4+kstep][512 ushorts = 1 KiB]; 16 KiB per buf per array
    __shared__ __align__(16) unsigned short ph_s[2][FT * 4][512];
    __shared__ __align__(16) unsigned short pl_s[2][FT * 4][512];
    __shared__ float norms_s[KCODE];

    // stage chunk c into buffer b: 32 x 1 KiB segments, 4 per wave, each a
    // global_load_lds dwordx4 (per-lane src = base + lane*16; LDS dest =
    // wave-uniform base + lane*16 -> linear, matches the read pattern).
    auto stage_chunk = [&](int c, int b) {
        int item = wave << 2;
#pragma unroll
        for (int t = 0; t < 4; ++t, ++item) {
            const int arr  = item >> 4;      // 0: ph, 1: pl
            const int sub  = item & 15;      // ti*4 + kstep
            const int tile = (c << 2) + (sub >> 2);
            const unsigned short* gs = (arr ? pl : ph)
                + ((size_t)(((tile << 2) + (sub & 3)) << 9) + (lane << 3));
            unsigned short* ld = arr ? &pl_s[b][sub][0] : &ph_s[b][sub][0];
            __builtin_amdgcn_global_load_lds(
                (const __attribute__((address_space(1))) void*)gs,
                (__attribute__((address_space(3))) void*)ld, 16, 0, 0);
        }
    };

    // issue chunk-0 staging first; latency hides under norms copy + A-build
    stage_chunk(0, 0);
    for (int i = threadIdx.x; i < KCODE; i += 512) norms_s[i] = norms[i];

    // ---- build A fragments (hi/lo), 4 k-steps ----
    // A layout (mirrors verified m120): A[row=lane&31][k=(lane>>5)*8+j]
    bf16x8 ah[4], al[4];
    {
        const float* xp = x + (size_t)(wrow + arow) * DDIM + half * 8;
#pragma unroll
        for (int s = 0; s < 4; ++s) {
            float4 v0 = *(const float4*)(xp + s * 16);
            float4 v1 = *(const float4*)(xp + s * 16 + 4);
            float f[8] = {v0.x, v0.y, v0.z, v0.w, v1.x, v1.y, v1.z, v1.w};
#pragma unroll
            for (int j = 0; j < 8; ++j) {
                unsigned short h = bf16_rne(f[j]);
                float hf = __uint_as_float((unsigned)h << 16);
                ah[s][j] = (short)h;
                al[s][j] = (short)bf16_rne(f[j] - hf);
            }
        }
    }

    // ---- per-lane running (min1, min2, argmin), 16 slots (C rows) ----
    float m1[16], m2[16];
    int   id[16];
#pragma unroll
    for (int r = 0; r < 16; ++r) { m1[r] = 3.4e38f; m2[r] = 3.4e38f; id[r] = 0; }

    __syncthreads();   // drains vmcnt (chunk-0 staged) + barrier

    for (int c = 0; c < NCHUNK; ++c) {
        const int b = c & 1;
        if (c + 1 < NCHUNK) stage_chunk(c + 1, b ^ 1);   // prefetch next chunk

        for (int ti = 0; ti < FT; ++ti) {
            const int tile = (c << 2) + ti;
            const int code = (tile << 5) | arow;          // this lane's C col
            const float nrm = norms_s[code];              // 2-way broadcast: free
            f32x16 acc = {0.f,0.f,0.f,0.f,0.f,0.f,0.f,0.f,
                          0.f,0.f,0.f,0.f,0.f,0.f,0.f,0.f};
            // hh,hl,lh per kstep: only 2 B-frags live at a time
#pragma unroll
            for (int s = 0; s < 4; ++s) {
                bf16x8 bh = *(const bf16x8*)&ph_s[b][(ti << 2) + s][lane << 3];
                bf16x8 bl = *(const bf16x8*)&pl_s[b][(ti << 2) + s][lane << 3];
                acc = __builtin_amdgcn_mfma_f32_32x32x16_bf16(ah[s], bh, acc, 0, 0, 0);
                acc = __builtin_amdgcn_mfma_f32_32x32x16_bf16(ah[s], bl, acc, 0, 0, 0);
                acc = __builtin_amdgcn_mfma_f32_32x32x16_bf16(al[s], bh, acc, 0, 0, 0);
            }
            // C layout (verified m74/m101): col=lane&31, row=(r&3)+8*(r>>2)+4*half
#pragma unroll
            for (int r = 0; r < 16; ++r) {
                float sv = fmaf(-2.0f, acc[r], nrm);
                // m2' = median(m1, m2, sv) == (sv<m1 ? m1 : min(m2,sv)), m1<=m2
                m2[r] = __builtin_amdgcn_fmed3f(m1[r], m2[r], sv);
                bool lt = sv < m1[r];
                m1[r] = lt ? sv : m1[r];
                id[r] = lt ? code : id[r];
            }
        }
        __syncthreads();   // all waves done with buf b; next chunk staged
    }

    // ---- cross-lane merge over the 32 code-columns (within each 32-lane half)
#pragma unroll
    for (int r = 0; r < 16; ++r) {
        float a1 = m1[r], a2 = m2[r];
        int   ai = id[r];
        for (int mask = 1; mask < 32; mask <<= 1) {
            float o1 = __shfl_xor(a1, mask, 64);
            float o2 = __shfl_xor(a2, mask, 64);
            int   oi = __shfl_xor(ai, mask, 64);
            float n2 = fminf(fminf(a2, o2), fmaxf(a1, o1));
            bool take = o1 < a1;
            a1 = take ? o1 : a1;
            ai = take ? oi : ai;
            a2 = n2;
        }
        m1[r] = a1; m2[r] = a2; id[r] = ai;
    }

    // After the merge, (m1,m2,id) are uniform across each 32-lane half, so
    // every lane computes its half's flag count (no divergence).
    int nf = 0;
#pragma unroll
    for (int r = 0; r < 16; ++r)
        nf += ((m2[r] - m1[r]) <= WINDOW) ? 1 : 0;

    // wave-aggregated worklist append: ONE atomic per wave
    int myoff = 0;
    if (list) {
        int nf0 = __shfl(nf, 0, 64);
        int nf1 = __shfl(nf, 32, 64);
        int wtotal = nf0 + nf1;
        int wbase = 0;
        if (lane == 0 && wtotal) wbase = atomicAdd(cnt, wtotal);
        wbase = __shfl(wbase, 0, 64);
        myoff = wbase + (half ? nf0 : 0);
    }

    if (arow == 0) {   // lanes 0 (half=0 rows) and 32 (half=1 rows) write
#pragma unroll
        for (int r = 0; r < 16; ++r) {
            int row = wrow + (r & 3) + 8 * (r >> 2) + 4 * half;
            bool flag = (m2[r] - m1[r]) <= WINDOW;
            idx[row] = flag ? (id[r] | 0x80000000) : id[r];
            if (list && flag) list[myoff++] = row;
        }
    }
}

// ------------------------------------------------------------------
// Rb: exact numpy rescore, one BLOCK per group of 4 worklist rows.
// Thread t owns codes k = 4t..4t+3 (ascending within thread; lexicographic
// (value,index) reduction across threads => global first-index argmin).
// Per d-step: one dwordx4 load of e[d][4t..4t+3] (wave reads a contiguous
// 1 KiB slice -> fully coalesced) + LDS broadcast of xs[r][d] + 16 chained
// FMAs (4 rows x 4 codes, independent chains -> issue-bound, latency hidden).
// Each chain's op order is IDENTICAL to vq_rescore: bit-exact.
__global__ __launch_bounds__(256) void vq_rescore_b(const float* __restrict__ x,
                                                    const float* __restrict__ e,   // [D][K]
                                                    const float* __restrict__ norms,
                                                    int* __restrict__ idx,
                                                    const int* __restrict__ cnt,
                                                    const int* __restrict__ list) {
#pragma clang fp contract(off)
    __shared__ float xs[4][DDIM];     // 4 staged rows
    __shared__ float sumxs[4];
    __shared__ int   rows_s[4];
    __shared__ float wval[4][4];      // [row][wave] lex-reduce partials
    __shared__ int   widx[4][4];

    const int tid  = threadIdx.x;
    const int lane = tid & 63;
    const int wave = tid >> 6;
    const int total = *cnt;
    const int ngroups = (total + 3) >> 2;

    const float* ep = e + (tid << 2);                       // e[0][4t]
    const float4 nv = *(const float4*)(norms + (tid << 2)); // norms[4t..4t+3]

    for (int g = blockIdx.x; g < ngroups; g += gridDim.x) {
        const int base = g * 4;
        const int nr = min(4, total - base);

        // ---- stage 4 rows into LDS (64 threads per row, stride-1: no conflicts)
        {
            int r = wave;            // tid>>6: one wave per row
            int d = lane;
            int row = (r < nr) ? list[base + r] : list[base];  // pad with row 0
            if (d == 0) rows_s[r] = row;
            xs[r][d] = x[(size_t)row * DDIM + d];
        }
        __syncthreads();

        // ---- sumsq per row: wave r computes row r with a bit-exact 16-lane tree.
        // u[j] on lane j (j<16); each xor level adds self+other, reproducing
        // numpy's pairwise order exactly (IEEE add is bitwise commutative).
        {
            int r = wave;
            float uj = 0.f;
            if (lane < 16) {
                float a0 = xs[r][lane];
                float a1 = xs[r][lane + 16];
                float a2 = xs[r][lane + 32];
                float a3 = xs[r][lane + 48];
                float p0 = a0 * a0, p1 = a1 * a1, p2 = a2 * a2, p3 = a3 * a3;
                uj = (p0 + p1) + (p2 + p3);
            }
            uj = uj + __shfl_xor(uj, 8, 64);   // v8[j] = u[j] + u[j+8]
            uj = uj + __shfl_xor(uj, 4, 64);   // w4[j] = v8[j] + v8[j+4]
            uj = uj + __shfl_xor(uj, 2, 64);   // y0 = w4[0]+w4[2] (lane0)
            uj = uj + __shfl_xor(uj, 1, 64);   // y0+y1 (lane0)
            if (lane == 0) sumxs[r] = uj;
        }
        __syncthreads();

        // ---- 16 independent sequential-d chains: 4 rows x 4 codes ----
        f32x4 a0 = {0.f, 0.f, 0.f, 0.f};
        f32x4 a1 = {0.f, 0.f, 0.f, 0.f};
        f32x4 a2 = {0.f, 0.f, 0.f, 0.f};
        f32x4 a3 = {0.f, 0.f, 0.f, 0.f};
#pragma unroll 8
        for (int d = 0; d < DDIM; ++d) {
            float4 ev = *(const float4*)(ep + (size_t)d * KCODE);
            float x0 = xs[0][d], x1 = xs[1][d], x2 = xs[2][d], x3 = xs[3][d];
            a0.x = fmaf(x0, ev.x, a0.x); a0.y = fmaf(x0, ev.y, a0.y);
            a0.z = fmaf(x0, ev.z, a0.z); a0.w = fmaf(x0, ev.w, a0.w);
            a1.x = fmaf(x1, ev.x, a1.x); a1.y = fmaf(x1, ev.y, a1.y);
            a1.z = fmaf(x1, ev.z, a1.z); a1.w = fmaf(x1, ev.w, a1.w);
            a2.x = fmaf(x2, ev.x, a2.x); a2.y = fmaf(x2, ev.y, a2.y);
            a2.z = fmaf(x2, ev.z, a2.z); a2.w = fmaf(x2, ev.w, a2.w);
            a3.x = fmaf(x3, ev.x, a3.x); a3.y = fmaf(x3, ev.y, a3.y);
            a3.z = fmaf(x3, ev.z, a3.z); a3.w = fmaf(x3, ev.w, a3.w);
        }

        // ---- per-row distances + lexicographic first-index argmin ----
#pragma unroll
        for (int r = 0; r < 4; ++r) {
            f32x4 ar = (r == 0) ? a0 : (r == 1) ? a1 : (r == 2) ? a2 : a3;
            float sx = sumxs[r];
            float bv = 3.4e38f; int bx = 0;
            {   // ascending k within thread: first-index on ties via strict <
                float t0 = sx + nv.x; float d0 = t0 - 2.0f * ar.x;
                if (d0 < bv) { bv = d0; bx = (tid << 2) + 0; }
                float t1 = sx + nv.y; float d1 = t1 - 2.0f * ar.y;
                if (d1 < bv) { bv = d1; bx = (tid << 2) + 1; }
                float t2 = sx + nv.z; float d2 = t2 - 2.0f * ar.z;
                if (d2 < bv) { bv = d2; bx = (tid << 2) + 2; }
                float t3 = sx + nv.w; float d3 = t3 - 2.0f * ar.w;
                if (d3 < bv) { bv = d3; bx = (tid << 2) + 3; }
            }
            for (int mask = 32; mask; mask >>= 1) {
                float ov = __shfl_xor(bv, mask, 64);
                int   ox = __shfl_xor(bx, mask, 64);
                if (ov < bv || (ov == bv && ox < bx)) { bv = ov; bx = ox; }
            }
            if (lane == 0) { wval[r][wave] = bv; widx[r][wave] = bx; }
        }
        __syncthreads();

        if (tid < nr) {
            float bv = wval[tid][0]; int bx = widx[tid][0];
#pragma unroll
            for (int w = 1; w < 4; ++w) {
                float ov = wval[tid][w]; int ox = widx[tid][w];
                if (ov < bv || (ov == bv && ox < bx)) { bv = ov; bx = ox; }
            }
            idx[rows_s[tid]] = bx;    // clears flag bit
        }
        __syncthreads();   // protect xs/rows_s/wval before next group
    }
}

// ------------------------------------------------------------------
// R (fallback, only if ws too small for the worklist): exact numpy rescore
// of flagged rows. One wave per row. UNCHANGED from verified version.
__global__ __launch_bounds__(256) void vq_rescore(const float* __restrict__ x,
                                                  const float* __restrict__ eT,
                                                  const float* __restrict__ norms,
                                                  int* __restrict__ idx) {
#pragma clang fp contract(off)
    const int wave = threadIdx.x >> 6;
    const int lane = threadIdx.x & 63;
    const int rowbase = blockIdx.x * 16 + wave * 4;   // 16384 blocks x 16 rows
    for (int i = 0; i < 4; ++i) {
        const int row = rowbase + i;
        if (idx[row] >= 0) continue;           // uniform branch (broadcast load)
        float xr[DDIM];
        const float4* xv = (const float4*)(x + (size_t)row * DDIM);
#pragma unroll
        for (int t = 0; t < DDIM / 4; ++t) {
            float4 v = xv[t];
            xr[4*t+0] = v.x; xr[4*t+1] = v.y; xr[4*t+2] = v.z; xr[4*t+3] = v.w;
        }
        float sumx = numpy_sumsq(xr);
        float best = 3.4e38f; int bi = 0;
        for (int j = 0; j < 16; ++j) {
            const int k = j * 64 + lane;       // ascending k per lane
            const float* __restrict__ ek = eT + (k << 6);
            float a = 0.f;
#pragma unroll
            for (int d = 0; d < DDIM; ++d)
                a = fmaf(xr[d], ek[d], a);     // strict sequential d-chain
            float t0 = sumx + norms[k];
            float dist = t0 - 2.0f * a;        // fl(fl(sumx+norm) - 2*dot)
            if (dist < best) { best = dist; bi = k; }
        }
        // lexicographic (value, index) min across 64 lanes = first-index argmin
        for (int mask = 32; mask; mask >>= 1) {
            float ov = __shfl_xor(best, mask, 64);
            int   oi = __shfl_xor(bi,   mask, 64);
            if (ov < best || (ov == best && oi < bi)) { best = ov; bi = oi; }
        }
        if (lane == 0) idx[row] = bi;          // clears flag bit
    }
}

// ------------------------------------------------------------------
// 2: gather + straight-through + per-BLOCK loss partial (UNCHANGED, verified)
__global__ __launch_bounds__(256) void vq_gather(const float* __restrict__ x,
                                                 const float* __restrict__ eT,
                                                 const int* __restrict__ idx,
                                                 float* __restrict__ out,
                                                 double* __restrict__ partials) {
#pragma clang fp contract(off)
    __shared__ float wsum[4];
    const int t   = blockIdx.x * 256 + threadIdx.x;   // NROWS*16 threads
    const int row = t >> 4;
    const int j   = t & 15;
    const int k   = idx[row];
    float4 q  = ((const float4*)eT)[(k << 4) + j];
    float4 xv = ((const float4*)x)[t];
    float dx = q.x - xv.x, dy = q.y - xv.y, dz = q.z - xv.z, dw = q.w - xv.w;
    float4 o;
    o.x = xv.x + dx; o.y = xv.y + dy; o.z = xv.z + dz; o.w = xv.w + dw;
    ((float4*)out)[t] = o;
    float s = dx*dx + dy*dy + dz*dz + dw*dw;
#pragma unroll
    for (int off = 32; off > 0; off >>= 1) s += __shfl_down(s, off, 64);
    if ((threadIdx.x & 63) == 0) wsum[threadIdx.x >> 6] = s;
    __syncthreads();
    if (threadIdx.x == 0) {
        double b = (double)wsum[0] + (double)wsum[1]
                 + (double)wsum[2] + (double)wsum[3];
        partials[blockIdx.x] = b;
    }
}

// ------------------------------------------------------------------
// 3: reduce block partials; loss = 1.25 * mse (UNCHANGED, verified)
__global__ __launch_bounds__(256) void vq_finalize(const double* __restrict__ partials,
                                                   float* __restrict__ out_loss) {
    __shared__ double sd[256];
    double a = 0.0;
    for (int i = threadIdx.x; i < GATHER_BLOCKS; i += 256) a += partials[i];
    sd[threadIdx.x] = a;
    __syncthreads();
    for (int s = 128; s > 0; s >>= 1) {
        if (threadIdx.x < s) sd[threadIdx.x] += sd[threadIdx.x + s];
        __syncthreads();
    }
    if (threadIdx.x == 0) {
        double mse = sd[0] / (double)((size_t)NROWS * DDIM);
        *out_loss = (float)(1.25 * mse);
    }
}

// ------------------------------------------------------------------
extern "C" void kernel_launch(void* const* d_in, const int* in_sizes, int n_in,
                              void* d_out, int out_size, void* d_ws, size_t ws_size,
                              hipStream_t stream) {
    const float* x = (const float*)d_in[0];        // [N, 64]
    const float* e = (const float*)d_in[1];        // [64, 1024]
    float* out = (float*)d_out;                    // [N*64 quantized_st] + [1 loss]

    char* ws = (char*)d_ws;
    float*          eT       = (float*)(ws + 0);
    float*          norms    = (float*)(ws + 262144);
    unsigned short* ph       = (unsigned short*)(ws + 266240);
    unsigned short* pl       = (unsigned short*)(ws + 397312);
    int*            idx      = (int*)(ws + 528384);
    double*         partials = (double*)(ws + 1576960);

    const size_t CNT_OFF  = 1708032;
    const size_t LIST_OFF = 1709056;
    const size_t REQUIRED = LIST_OFF + (size_t)NROWS * 4;   // ~2.63 MiB
    const bool compact = (ws_size >= REQUIRED);
    int* cnt  = compact ? (int*)(ws + CNT_OFF)  : (int*)0;
    int* list = compact ? (int*)(ws + LIST_OFF) : (int*)0;

    vq_prep    <<<KCODE / 256,   256, 0, stream>>>(e, eT, norms, ph, pl, cnt);
    vq_filter  <<<NROWS / 256,   512, 0, stream>>>(x, ph, pl, norms, idx, cnt, list);
    if (compact)
        vq_rescore_b<<<2048,     256, 0, stream>>>(x, e, norms, idx, cnt, list);
    else
        vq_rescore  <<<NROWS/16, 256, 0, stream>>>(x, eT, norms, idx);
    vq_gather  <<<GATHER_BLOCKS, 256, 0, stream>>>(x, eT, idx, out, partials);
    vq_finalize<<<1,             256, 0, stream>>>(partials, out + (size_t)NROWS * DDIM);
}

// Round 8
// 327.426 us; speedup vs baseline: 1.5390x; 1.5390x over previous
//
#include <hip/hip_runtime.h>

#define NROWS 262144   // 256*32*32
#define DDIM  64
#define KCODE 1024
#define GATHER_BLOCKS ((NROWS * 16) / 256)   // 16384
#define WINDOW 4e-3f   // certified: worst-case |approx_s - numpy_s| < 1.6e-3; 2.5x margin

// ---- ws layout (bytes) ----
// [0)        eT       float[KCODE*DDIM]   = 262144 B  (codebook transposed, [k][d])
// [262144)   norms    float[KCODE]        = 4096 B    (numpy-order sum of squares)
// [266240)   ph       ushort[32*4*64*8]   = 131072 B  (bf16 hi of -2*e, 32x32-packed)
// [397312)   pl       ushort[32*4*64*8]   = 131072 B  (bf16 lo of -2*e, 32x32-packed)
// [528384)   idx      int[NROWS]          = 1 MiB     (bit31 = needs exact rescore)
// [1576960)  partials double[16384]       = 128 KiB
// [1708032)  cnt      int                 (compact-list counter, zeroed by vq_prep)
// [1709056)  list     int[NROWS]          = 1 MiB     (compacted flagged-row worklist)
//
// Fragment pack (32x32x16): ph/pl[((tile*4+kstep)<<9) + lane*8 + j] holds bf16
// hi/lo of  -2 * e  at dim d = kstep*16 + (lane>>5)*8 + j of code
// k = tile*32 + (lane&31) — the exact B lane-fragment of mfma_f32_32x32x16_bf16
// (C layout HW-verified m74/m101). The -2 pre-scale is EXACT (pow-2 scaling
// commutes with bf16 RNE; |v|<0.05 so no overflow; hi/lo splits scale exactly),
// so MFMA with acc initialized to norm_k yields sv = norm - 2*dot directly:
// the 16 fmaf/tile of the old epilogue fold into the (free) accumulator init.
//
// ROUND-8 RATIONALE (counter-derived): r7's 512-thread staged variant SPILLED
// (WRITE_SIZE 687 MB scratch, 343 us) — staging abandoned (r5 neutral, r7
// spill; r6 L2 throughput 14.4 TB/s << 34.5 ceiling -> L2-BW was NOT binding).
// r6's real profile: VALU 63 us > MFMA 45 us (~floor), rest = dependency
// bubbles (12-MFMA serial chain per tile, tracker depends on chain end).
// Fixes: (1) -2-pack + acc=nrm init kills 16 fmaf/tile; (2) m1 via fminf
// (tracker 5->4 ops); (3) #pragma unroll 2 on tile loop — adjacent tiles'
// MFMA chains are independent -> scheduler interleaves, filling latency holes.
// Tripwires: WRITE_SIZE >> 2 MB or VGPR > 128 next round = spill, revert #3.
//
// SEMANTICS (verified bit-exact, absmax 0.0): oracle = numpy fp32,
// AVX512 pairwise sumsq, sequential-d fp32-FMA dot, dist = fl(fl(sumx+norm)-2dot),
// first-index argmin, out = fl(x + fl(q-x)). Exact path preserved in vq_prep /
// vq_rescore* / vq_gather. vq_filter is APPROXIMATE with a certified window;
// near-ties are rescored exactly. The acc-init refold changes approx-score
// rounding by a few ulps only — absorbed by the 2.5x window margin. med3 for
// m2 is provably exact given the m1<=m2 invariant.
//
// HISTORY (counter-verified):
//  rescore: r0 305us latency -> r1 spill 626us BAD -> r2 348us serialized
//           -> r3 vq_rescore_b block-per-4-rows: off top-5 (<40us). GOOD.
//  filter:  r3 253us divergent-B -> r4 166us fragment-packed -> r5 167us LDS
//           staging NEUTRAL (wrong regime) -> r6 146us 32x32 MFMA (VALU-heavy,
//           bubble-limited) -> r7 512t+staging SPILL 343us BAD.

typedef short bf16x8 __attribute__((ext_vector_type(8)));
typedef float f32x4  __attribute__((ext_vector_type(4)));
typedef float f32x16 __attribute__((ext_vector_type(16)));

__device__ __forceinline__ unsigned short bf16_rne(float f) {
    unsigned u = __float_as_uint(f);
    unsigned r = u + 0x7fffu + ((u >> 16) & 1u);
    return (unsigned short)(r >> 16);
}

// ------------------------------------------------------------------
// P: transpose codebook, numpy-order norms, 32x32-fragment-packed bf16 hi/lo
// of -2*e, zero worklist cnt
__global__ __launch_bounds__(256) void vq_prep(const float* __restrict__ e,
                                               float* __restrict__ eT,
                                               float* __restrict__ norms,
                                               unsigned short* __restrict__ ph,
                                               unsigned short* __restrict__ pl,
                                               int* cnt) {
#pragma clang fp contract(off)
    if (cnt && blockIdx.x == 0 && threadIdx.x == 0) *cnt = 0;
    const int k = blockIdx.x * 256 + threadIdx.x;   // 4 blocks x 256 = 1024
    const int tile = k >> 5;          // 32 codes per 32x32 tile
    const int col  = k & 31;
    float acc = 0.0f;
    for (int d = 0; d < DDIM; ++d) {
        float v = e[d * KCODE + k];      // e is [D][K]; coalesced across k-lanes
        eT[(k << 6) + d] = v;
        // pack -2*v (exact pow-2 scale; |v|<0.05): filter's MFMA then
        // accumulates -2*dot directly on top of acc=norm.
        float v2 = -2.0f * v;
        unsigned short h = bf16_rne(v2);
        float hf = __uint_as_float((unsigned)h << 16);
        // B-fragment pack: kstep = d>>4, lane = ((d&15)>>3)*32 + col, j = d&7
        const int kstep = d >> 4;
        const int lane  = (((d & 15) >> 3) << 5) | col;
        const int pidx  = (((tile << 2) + kstep) << 9) + (lane << 3) + (d & 7);
        ph[pidx] = h;
        pl[pidx] = bf16_rne(v2 - hf);    // Sterbenz: v2-hf exact
        float sq = v * v;                // rounded square (numpy elementwise mul)
        acc = acc + sq;                  // sequential adds (numpy axis-0 reduce)
    }
    norms[k] = acc;
}

// ------------------------------------------------------------------
// numpy AVX512 pairwise sum of fl(x_d^2) — exact op order, do not touch
__device__ __forceinline__ float numpy_sumsq(const float* xr) {
#pragma clang fp contract(off)
    float u[16];
#pragma unroll
    for (int j = 0; j < 16; ++j) {
        float p0 = xr[j     ] * xr[j     ];
        float p1 = xr[j + 16] * xr[j + 16];
        float p2 = xr[j + 32] * xr[j + 32];
        float p3 = xr[j + 48] * xr[j + 48];
        u[j] = (p0 + p1) + (p2 + p3);
    }
    float v8[8];
#pragma unroll
    for (int j = 0; j < 8; ++j) v8[j] = u[j] + u[j + 8];
    float w4[4];
#pragma unroll
    for (int j = 0; j < 4; ++j) w4[j] = v8[j] + v8[j + 4];
    float y0 = w4[0] + w4[2];
    float y1 = w4[1] + w4[3];
    return y0 + y1;
}

// ------------------------------------------------------------------
// 1: 32x32x16-MFMA split-bf16 approximate argmin. Wave = 32 rows x 1024 codes.
// Per k-tile: acc initialized to norm_k, 12 MFMAs accumulate -2*dot (hh,hl,lh
// per kstep with the -2-scaled pack) -> sv = acc[r] directly. Tracker is 4 ops
// per distance (med3, cmp, cndmask-id, min). Tile loop unrolled x2 so two
// independent MFMA chains interleave (fills latency bubbles).
__global__ __launch_bounds__(256, 4) void vq_filter(const float* __restrict__ x,
                                                    const unsigned short* __restrict__ ph,
                                                    const unsigned short* __restrict__ pl,
                                                    const float* __restrict__ norms,
                                                    int* __restrict__ idx,
                                                    int* cnt,
                                                    int* list) {
    const int lane = threadIdx.x & 63;
    const int wave = threadIdx.x >> 6;
    const int wrow = blockIdx.x * 128 + wave * 32;   // 32 rows per wave
    const int arow = lane & 31;       // A row / C col-class
    const int half = lane >> 5;       // A k-group / C row-half

    // ---- build A fragments (hi/lo), 4 k-steps ----
    // A layout (mirrors verified m120): A[row=lane&31][k=(lane>>5)*8+j]
    bf16x8 ah[4], al[4];
    {
        const float* xp = x + (size_t)(wrow + arow) * DDIM + half * 8;
#pragma unroll
        for (int s = 0; s < 4; ++s) {
            float4 v0 = *(const float4*)(xp + s * 16);
            float4 v1 = *(const float4*)(xp + s * 16 + 4);
            float f[8] = {v0.x, v0.y, v0.z, v0.w, v1.x, v1.y, v1.z, v1.w};
#pragma unroll
            for (int j = 0; j < 8; ++j) {
                unsigned short h = bf16_rne(f[j]);
                float hf = __uint_as_float((unsigned)h << 16);
                ah[s][j] = (short)h;
                al[s][j] = (short)bf16_rne(f[j] - hf);
            }
        }
    }

    // ---- per-lane running (min1, min2, argmin), 16 slots (C rows) ----
    float m1[16], m2[16];
    int   id[16];
#pragma unroll
    for (int r = 0; r < 16; ++r) { m1[r] = 3.4e38f; m2[r] = 3.4e38f; id[r] = 0; }

    const bf16x8* __restrict__ phv = (const bf16x8*)ph;
    const bf16x8* __restrict__ plv = (const bf16x8*)pl;

#pragma unroll 2
    for (int tile = 0; tile < KCODE / 32; ++tile) {
        const int code = (tile << 5) | arow;          // this lane's C col
        const float nrm = norms[code];                // coalesced 128B per group
        // acc starts at norm_k; MFMAs add -2*dot (pack is -2-scaled)
        f32x16 acc = {nrm,nrm,nrm,nrm,nrm,nrm,nrm,nrm,
                      nrm,nrm,nrm,nrm,nrm,nrm,nrm,nrm};
        // hh,hl,lh per kstep: only 2 B-frags live at a time
#pragma unroll
        for (int s = 0; s < 4; ++s) {
            const int fb = (((tile << 2) + s) << 6) + lane;
            bf16x8 bh = phv[fb];
            bf16x8 bl = plv[fb];
            acc = __builtin_amdgcn_mfma_f32_32x32x16_bf16(ah[s], bh, acc, 0, 0, 0);
            acc = __builtin_amdgcn_mfma_f32_32x32x16_bf16(ah[s], bl, acc, 0, 0, 0);
            acc = __builtin_amdgcn_mfma_f32_32x32x16_bf16(al[s], bh, acc, 0, 0, 0);
        }
        // C layout (verified m74/m101): col=lane&31, row=(r&3)+8*(r>>2)+4*half
#pragma unroll
        for (int r = 0; r < 16; ++r) {
            float sv = acc[r];                       // = norm - 2*dot (approx)
            // m2' = median(m1, m2, sv) == (sv<m1 ? m1 : min(m2,sv)) given m1<=m2
            m2[r] = __builtin_amdgcn_fmed3f(m1[r], m2[r], sv);
            bool lt = sv < m1[r];
            id[r] = lt ? code : id[r];
            m1[r] = fminf(m1[r], sv);
        }
    }

    // ---- cross-lane merge over the 32 code-columns (within each 32-lane half)
#pragma unroll
    for (int r = 0; r < 16; ++r) {
        float a1 = m1[r], a2 = m2[r];
        int   ai = id[r];
        for (int mask = 1; mask < 32; mask <<= 1) {
            float o1 = __shfl_xor(a1, mask, 64);
            float o2 = __shfl_xor(a2, mask, 64);
            int   oi = __shfl_xor(ai, mask, 64);
            float n2 = fminf(fminf(a2, o2), fmaxf(a1, o1));
            bool take = o1 < a1;
            a1 = take ? o1 : a1;
            ai = take ? oi : ai;
            a2 = n2;
        }
        m1[r] = a1; m2[r] = a2; id[r] = ai;
    }

    // After the merge, (m1,m2,id) are uniform across each 32-lane half, so
    // every lane computes its half's flag count (no divergence).
    int nf = 0;
#pragma unroll
    for (int r = 0; r < 16; ++r)
        nf += ((m2[r] - m1[r]) <= WINDOW) ? 1 : 0;

    // wave-aggregated worklist append: ONE atomic per wave
    int myoff = 0;
    if (list) {
        int nf0 = __shfl(nf, 0, 64);
        int nf1 = __shfl(nf, 32, 64);
        int wtotal = nf0 + nf1;
        int wbase = 0;
        if (lane == 0 && wtotal) wbase = atomicAdd(cnt, wtotal);
        wbase = __shfl(wbase, 0, 64);
        myoff = wbase + (half ? nf0 : 0);
    }

    if (arow == 0) {   // lanes 0 (half=0 rows) and 32 (half=1 rows) write
#pragma unroll
        for (int r = 0; r < 16; ++r) {
            int row = wrow + (r & 3) + 8 * (r >> 2) + 4 * half;
            bool flag = (m2[r] - m1[r]) <= WINDOW;
            idx[row] = flag ? (id[r] | 0x80000000) : id[r];
            if (list && flag) list[myoff++] = row;
        }
    }
}

// ------------------------------------------------------------------
// Rb: exact numpy rescore, one BLOCK per group of 4 worklist rows.
// Thread t owns codes k = 4t..4t+3 (ascending within thread; lexicographic
// (value,index) reduction across threads => global first-index argmin).
// Per d-step: one dwordx4 load of e[d][4t..4t+3] (wave reads a contiguous
// 1 KiB slice -> fully coalesced) + LDS broadcast of xs[r][d] + 16 chained
// FMAs (4 rows x 4 codes, independent chains -> issue-bound, latency hidden).
// Each chain's op order is IDENTICAL to vq_rescore: bit-exact.
__global__ __launch_bounds__(256) void vq_rescore_b(const float* __restrict__ x,
                                                    const float* __restrict__ e,   // [D][K]
                                                    const float* __restrict__ norms,
                                                    int* __restrict__ idx,
                                                    const int* __restrict__ cnt,
                                                    const int* __restrict__ list) {
#pragma clang fp contract(off)
    __shared__ float xs[4][DDIM];     // 4 staged rows
    __shared__ float sumxs[4];
    __shared__ int   rows_s[4];
    __shared__ float wval[4][4];      // [row][wave] lex-reduce partials
    __shared__ int   widx[4][4];

    const int tid  = threadIdx.x;
    const int lane = tid & 63;
    const int wave = tid >> 6;
    const int total = *cnt;
    const int ngroups = (total + 3) >> 2;

    const float* ep = e + (tid << 2);                       // e[0][4t]
    const float4 nv = *(const float4*)(norms + (tid << 2)); // norms[4t..4t+3]

    for (int g = blockIdx.x; g < ngroups; g += gridDim.x) {
        const int base = g * 4;
        const int nr = min(4, total - base);

        // ---- stage 4 rows into LDS (64 threads per row, stride-1: no conflicts)
        {
            int r = wave;            // tid>>6: one wave per row
            int d = lane;
            int row = (r < nr) ? list[base + r] : list[base];  // pad with row 0
            if (d == 0) rows_s[r] = row;
            xs[r][d] = x[(size_t)row * DDIM + d];
        }
        __syncthreads();

        // ---- sumsq per row: wave r computes row r with a bit-exact 16-lane tree.
        // u[j] on lane j (j<16); each xor level adds self+other, reproducing
        // numpy's pairwise order exactly (IEEE add is bitwise commutative).
        {
            int r = wave;
            float uj = 0.f;
            if (lane < 16) {
                float a0 = xs[r][lane];
                float a1 = xs[r][lane + 16];
                float a2 = xs[r][lane + 32];
                float a3 = xs[r][lane + 48];
                float p0 = a0 * a0, p1 = a1 * a1, p2 = a2 * a2, p3 = a3 * a3;
                uj = (p0 + p1) + (p2 + p3);
            }
            uj = uj + __shfl_xor(uj, 8, 64);   // v8[j] = u[j] + u[j+8]
            uj = uj + __shfl_xor(uj, 4, 64);   // w4[j] = v8[j] + v8[j+4]
            uj = uj + __shfl_xor(uj, 2, 64);   // y0 = w4[0]+w4[2] (lane0)
            uj = uj + __shfl_xor(uj, 1, 64);   // y0+y1 (lane0)
            if (lane == 0) sumxs[r] = uj;
        }
        __syncthreads();

        // ---- 16 independent sequential-d chains: 4 rows x 4 codes ----
        f32x4 a0 = {0.f, 0.f, 0.f, 0.f};
        f32x4 a1 = {0.f, 0.f, 0.f, 0.f};
        f32x4 a2 = {0.f, 0.f, 0.f, 0.f};
        f32x4 a3 = {0.f, 0.f, 0.f, 0.f};
#pragma unroll 8
        for (int d = 0; d < DDIM; ++d) {
            float4 ev = *(const float4*)(ep + (size_t)d * KCODE);
            float x0 = xs[0][d], x1 = xs[1][d], x2 = xs[2][d], x3 = xs[3][d];
            a0.x = fmaf(x0, ev.x, a0.x); a0.y = fmaf(x0, ev.y, a0.y);
            a0.z = fmaf(x0, ev.z, a0.z); a0.w = fmaf(x0, ev.w, a0.w);
            a1.x = fmaf(x1, ev.x, a1.x); a1.y = fmaf(x1, ev.y, a1.y);
            a1.z = fmaf(x1, ev.z, a1.z); a1.w = fmaf(x1, ev.w, a1.w);
            a2.x = fmaf(x2, ev.x, a2.x); a2.y = fmaf(x2, ev.y, a2.y);
            a2.z = fmaf(x2, ev.z, a2.z); a2.w = fmaf(x2, ev.w, a2.w);
            a3.x = fmaf(x3, ev.x, a3.x); a3.y = fmaf(x3, ev.y, a3.y);
            a3.z = fmaf(x3, ev.z, a3.z); a3.w = fmaf(x3, ev.w, a3.w);
        }

        // ---- per-row distances + lexicographic first-index argmin ----
#pragma unroll
        for (int r = 0; r < 4; ++r) {
            f32x4 ar = (r == 0) ? a0 : (r == 1) ? a1 : (r == 2) ? a2 : a3;
            float sx = sumxs[r];
            float bv = 3.4e38f; int bx = 0;
            {   // ascending k within thread: first-index on ties via strict <
                float t0 = sx + nv.x; float d0 = t0 - 2.0f * ar.x;
                if (d0 < bv) { bv = d0; bx = (tid << 2) + 0; }
                float t1 = sx + nv.y; float d1 = t1 - 2.0f * ar.y;
                if (d1 < bv) { bv = d1; bx = (tid << 2) + 1; }
                float t2 = sx + nv.z; float d2 = t2 - 2.0f * ar.z;
                if (d2 < bv) { bv = d2; bx = (tid << 2) + 2; }
                float t3 = sx + nv.w; float d3 = t3 - 2.0f * ar.w;
                if (d3 < bv) { bv = d3; bx = (tid << 2) + 3; }
            }
            for (int mask = 32; mask; mask >>= 1) {
                float ov = __shfl_xor(bv, mask, 64);
                int   ox = __shfl_xor(bx, mask, 64);
                if (ov < bv || (ov == bv && ox < bx)) { bv = ov; bx = ox; }
            }
            if (lane == 0) { wval[r][wave] = bv; widx[r][wave] = bx; }
        }
        __syncthreads();

        if (tid < nr) {
            float bv = wval[tid][0]; int bx = widx[tid][0];
#pragma unroll
            for (int w = 1; w < 4; ++w) {
                float ov = wval[tid][w]; int ox = widx[tid][w];
                if (ov < bv || (ov == bv && ox < bx)) { bv = ov; bx = ox; }
            }
            idx[rows_s[tid]] = bx;    // clears flag bit
        }
        __syncthreads();   // protect xs/rows_s/wval before next group
    }
}

// ------------------------------------------------------------------
// R (fallback, only if ws too small for the worklist): exact numpy rescore
// of flagged rows. One wave per row. UNCHANGED from verified version.
__global__ __launch_bounds__(256) void vq_rescore(const float* __restrict__ x,
                                                  const float* __restrict__ eT,
                                                  const float* __restrict__ norms,
                                                  int* __restrict__ idx) {
#pragma clang fp contract(off)
    const int wave = threadIdx.x >> 6;
    const int lane = threadIdx.x & 63;
    const int rowbase = blockIdx.x * 16 + wave * 4;   // 16384 blocks x 16 rows
    for (int i = 0; i < 4; ++i) {
        const int row = rowbase + i;
        if (idx[row] >= 0) continue;           // uniform branch (broadcast load)
        float xr[DDIM];
        const float4* xv = (const float4*)(x + (size_t)row * DDIM);
#pragma unroll
        for (int t = 0; t < DDIM / 4; ++t) {
            float4 v = xv[t];
            xr[4*t+0] = v.x; xr[4*t+1] = v.y; xr[4*t+2] = v.z; xr[4*t+3] = v.w;
        }
        float sumx = numpy_sumsq(xr);
        float best = 3.4e38f; int bi = 0;
        for (int j = 0; j < 16; ++j) {
            const int k = j * 64 + lane;       // ascending k per lane
            const float* __restrict__ ek = eT + (k << 6);
            float a = 0.f;
#pragma unroll
            for (int d = 0; d < DDIM; ++d)
                a = fmaf(xr[d], ek[d], a);     // strict sequential d-chain
            float t0 = sumx + norms[k];
            float dist = t0 - 2.0f * a;        // fl(fl(sumx+norm) - 2*dot)
            if (dist < best) { best = dist; bi = k; }
        }
        // lexicographic (value, index) min across 64 lanes = first-index argmin
        for (int mask = 32; mask; mask >>= 1) {
            float ov = __shfl_xor(best, mask, 64);
            int   oi = __shfl_xor(bi,   mask, 64);
            if (ov < best || (ov == best && oi < bi)) { best = ov; bi = oi; }
        }
        if (lane == 0) idx[row] = bi;          // clears flag bit
    }
}

// ------------------------------------------------------------------
// 2: gather + straight-through + per-BLOCK loss partial (UNCHANGED, verified)
__global__ __launch_bounds__(256) void vq_gather(const float* __restrict__ x,
                                                 const float* __restrict__ eT,
                                                 const int* __restrict__ idx,
                                                 float* __restrict__ out,
                                                 double* __restrict__ partials) {
#pragma clang fp contract(off)
    __shared__ float wsum[4];
    const int t   = blockIdx.x * 256 + threadIdx.x;   // NROWS*16 threads
    const int row = t >> 4;
    const int j   = t & 15;
    const int k   = idx[row];
    float4 q  = ((const float4*)eT)[(k << 4) + j];
    float4 xv = ((const float4*)x)[t];
    float dx = q.x - xv.x, dy = q.y - xv.y, dz = q.z - xv.z, dw = q.w - xv.w;
    float4 o;
    o.x = xv.x + dx; o.y = xv.y + dy; o.z = xv.z + dz; o.w = xv.w + dw;
    ((float4*)out)[t] = o;
    float s = dx*dx + dy*dy + dz*dz + dw*dw;
#pragma unroll
    for (int off = 32; off > 0; off >>= 1) s += __shfl_down(s, off, 64);
    if ((threadIdx.x & 63) == 0) wsum[threadIdx.x >> 6] = s;
    __syncthreads();
    if (threadIdx.x == 0) {
        double b = (double)wsum[0] + (double)wsum[1]
                 + (double)wsum[2] + (double)wsum[3];
        partials[blockIdx.x] = b;
    }
}

// ------------------------------------------------------------------
// 3: reduce block partials; loss = 1.25 * mse (UNCHANGED, verified)
__global__ __launch_bounds__(256) void vq_finalize(const double* __restrict__ partials,
                                                   float* __restrict__ out_loss) {
    __shared__ double sd[256];
    double a = 0.0;
    for (int i = threadIdx.x; i < GATHER_BLOCKS; i += 256) a += partials[i];
    sd[threadIdx.x] = a;
    __syncthreads();
    for (int s = 128; s > 0; s >>= 1) {
        if (threadIdx.x < s) sd[threadIdx.x] += sd[threadIdx.x + s];
        __syncthreads();
    }
    if (threadIdx.x == 0) {
        double mse = sd[0] / (double)((size_t)NROWS * DDIM);
        *out_loss = (float)(1.25 * mse);
    }
}

// ------------------------------------------------------------------
extern "C" void kernel_launch(void* const* d_in, const int* in_sizes, int n_in,
                              void* d_out, int out_size, void* d_ws, size_t ws_size,
                              hipStream_t stream) {
    const float* x = (const float*)d_in[0];        // [N, 64]
    const float* e = (const float*)d_in[1];        // [64, 1024]
    float* out = (float*)d_out;                    // [N*64 quantized_st] + [1 loss]

    char* ws = (char*)d_ws;
    float*          eT       = (float*)(ws + 0);
    float*          norms    = (float*)(ws + 262144);
    unsigned short* ph       = (unsigned short*)(ws + 266240);
    unsigned short* pl       = (unsigned short*)(ws + 397312);
    int*            idx      = (int*)(ws + 528384);
    double*         partials = (double*)(ws + 1576960);

    const size_t CNT_OFF  = 1708032;
    const size_t LIST_OFF = 1709056;
    const size_t REQUIRED = LIST_OFF + (size_t)NROWS * 4;   // ~2.63 MiB
    const bool compact = (ws_size >= REQUIRED);
    int* cnt  = compact ? (int*)(ws + CNT_OFF)  : (int*)0;
    int* list = compact ? (int*)(ws + LIST_OFF) : (int*)0;

    vq_prep    <<<KCODE / 256,   256, 0, stream>>>(e, eT, norms, ph, pl, cnt);
    vq_filter  <<<NROWS / 128,   256, 0, stream>>>(x, ph, pl, norms, idx, cnt, list);
    if (compact)
        vq_rescore_b<<<2048,     256, 0, stream>>>(x, e, norms, idx, cnt, list);
    else
        vq_rescore  <<<NROWS/16, 256, 0, stream>>>(x, eT, norms, idx);
    vq_gather  <<<GATHER_BLOCKS, 256, 0, stream>>>(x, eT, idx, out, partials);
    vq_finalize<<<1,             256, 0, stream>>>(partials, out + (size_t)NROWS * DDIM);
}

// Round 9
// 299.240 us; speedup vs baseline: 1.6839x; 1.0942x over previous
//
#include <hip/hip_runtime.h>

#define NROWS 262144   // 256*32*32
#define DDIM  64
#define KCODE 1024
#define GATHER_BLOCKS ((NROWS * 16) / 256)   // 16384
#define WINDOW 4e-3f   // certified: worst-case |approx_s - numpy_s| < 1.6e-3; 2.5x margin

// ---- ws layout (bytes) ----
// [0)        eT       float[KCODE*DDIM]   = 262144 B  (codebook transposed, [k][d])
// [262144)   norms    float[KCODE]        = 4096 B    (numpy-order sum of squares)
// [266240)   ph       ushort[32*4*64*8]   = 131072 B  (bf16 hi, 32x32-fragment-packed)
// [397312)   pl       ushort[32*4*64*8]   = 131072 B  (bf16 lo, 32x32-fragment-packed)
// [528384)   idx      int[NROWS]          = 1 MiB     (bit31 = needs exact rescore)
// [1576960)  partials double[16384]       = 128 KiB
// [1708032)  cnt      int                 (compact-list counter, zeroed by vq_prep)
// [1709056)  list     int[NROWS]          = 1 MiB     (compacted flagged-row worklist)
//
// Fragment pack (32x32x16): ph/pl[((tile*4+kstep)<<9) + lane*8 + j] holds bf16
// hi/lo of dim d = kstep*16 + (lane>>5)*8 + j of code k = tile*32 + (lane&31) —
// the exact B lane-fragment of mfma_f32_32x32x16_bf16 (C layout HW-verified
// m74/m101). Loads are 64 lanes x contiguous 16 B.
//
// ROUND-9 RATIONALE (counter-derived): r8 (acc=nrm init + -2 pack + unroll2)
// REGRESSED 146->165, MfmaUtil 31->27: the nrm broadcast cost 16 movs (= the
// 16 fmaf "saved") AND put the norms L2 load at the head of every MFMA chain.
// Theory: r6's 146us vs 41us MFMA floor is per-tile serial structure (8 loads
// -> ~300cy wait -> 12-MFMA dep chain -> tracker). Fix = ONE mechanism: manual
// 2-stage register pipeline. k0/k1 frags of tile t+1 load during t's MFMAs;
// k2/k3 of t issue at tile top and hide under k0/k1's chain. No load at any
// chain head. B regs = 8 frags (32 VGPR), named (no runtime-indexed arrays,
// rule #20). launch_bounds(256,3): 3 waves x ~140 regs <= 512/SIMD.
// Tripwires: VGPR > 170 or WRITE_SIZE >> 2 MB = spill, revert to r6.
//
// SEMANTICS (verified bit-exact, absmax 0.0): oracle = numpy fp32,
// AVX512 pairwise sumsq, sequential-d fp32-FMA dot, dist = fl(fl(sumx+norm)-2dot),
// first-index argmin, out = fl(x + fl(q-x)). Exact path preserved in vq_prep /
// vq_rescore* / vq_gather. vq_filter is APPROXIMATE with a certified window;
// near-ties are rescored exactly. med3 for m2 is provably exact given the
// m1<=m2 invariant. Filter math/bytes identical to r6 (pipeline only reorders
// loads).
//
// HISTORY (counter-verified):
//  rescore: r0 305us latency -> r1 spill 626us BAD -> r2 348us serialized
//           -> r3 vq_rescore_b block-per-4-rows: off top-5 (<40us). GOOD.
//  filter:  r3 253us divergent-B -> r4 166us fragment-packed -> r5 167us LDS
//           staging NEUTRAL (wrong regime) -> r6 146us 32x32 MFMA -> r7 512t
//           staging SPILL 343us BAD -> r8 acc-init refold REGRESSED 165us
//           (load at chain head).

typedef short bf16x8 __attribute__((ext_vector_type(8)));
typedef float f32x4  __attribute__((ext_vector_type(4)));
typedef float f32x16 __attribute__((ext_vector_type(16)));

__device__ __forceinline__ unsigned short bf16_rne(float f) {
    unsigned u = __float_as_uint(f);
    unsigned r = u + 0x7fffu + ((u >> 16) & 1u);
    return (unsigned short)(r >> 16);
}

// ------------------------------------------------------------------
// P: transpose codebook, numpy-order norms, 32x32-fragment-packed bf16 hi/lo,
// zero worklist cnt (r6 version, verbatim)
__global__ __launch_bounds__(256) void vq_prep(const float* __restrict__ e,
                                               float* __restrict__ eT,
                                               float* __restrict__ norms,
                                               unsigned short* __restrict__ ph,
                                               unsigned short* __restrict__ pl,
                                               int* cnt) {
#pragma clang fp contract(off)
    if (cnt && blockIdx.x == 0 && threadIdx.x == 0) *cnt = 0;
    const int k = blockIdx.x * 256 + threadIdx.x;   // 4 blocks x 256 = 1024
    const int tile = k >> 5;          // 32 codes per 32x32 tile
    const int col  = k & 31;
    float acc = 0.0f;
    for (int d = 0; d < DDIM; ++d) {
        float v = e[d * KCODE + k];      // e is [D][K]; coalesced across k-lanes
        eT[(k << 6) + d] = v;
        unsigned short h = bf16_rne(v);
        float hf = __uint_as_float((unsigned)h << 16);
        // B-fragment pack: kstep = d>>4, lane = ((d&15)>>3)*32 + col, j = d&7
        const int kstep = d >> 4;
        const int lane  = (((d & 15) >> 3) << 5) | col;
        const int pidx  = (((tile << 2) + kstep) << 9) + (lane << 3) + (d & 7);
        ph[pidx] = h;
        pl[pidx] = bf16_rne(v - hf);     // Sterbenz: v-hf exact
        float sq = v * v;                // rounded square (numpy elementwise mul)
        acc = acc + sq;                  // sequential adds (numpy axis-0 reduce)
    }
    norms[k] = acc;
}

// ------------------------------------------------------------------
// numpy AVX512 pairwise sum of fl(x_d^2) — exact op order, do not touch
__device__ __forceinline__ float numpy_sumsq(const float* xr) {
#pragma clang fp contract(off)
    float u[16];
#pragma unroll
    for (int j = 0; j < 16; ++j) {
        float p0 = xr[j     ] * xr[j     ];
        float p1 = xr[j + 16] * xr[j + 16];
        float p2 = xr[j + 32] * xr[j + 32];
        float p3 = xr[j + 48] * xr[j + 48];
        u[j] = (p0 + p1) + (p2 + p3);
    }
    float v8[8];
#pragma unroll
    for (int j = 0; j < 8; ++j) v8[j] = u[j] + u[j + 8];
    float w4[4];
#pragma unroll
    for (int j = 0; j < 4; ++j) w4[j] = v8[j] + v8[j + 4];
    float y0 = w4[0] + w4[2];
    float y1 = w4[1] + w4[3];
    return y0 + y1;
}

// ------------------------------------------------------------------
// 1: 32x32x16-MFMA split-bf16 approximate argmin. Wave = 32 rows x 1024 codes.
// Per k-tile: 12 MFMAs (hh,hl,lh per kstep), 16 track slots/lane. B-fragment
// loads are software-pipelined across tiles (see ROUND-9 note above).
__global__ __launch_bounds__(256, 3) void vq_filter(const float* __restrict__ x,
                                                    const unsigned short* __restrict__ ph,
                                                    const unsigned short* __restrict__ pl,
                                                    const float* __restrict__ norms,
                                                    int* __restrict__ idx,
                                                    int* cnt,
                                                    int* list) {
    const int lane = threadIdx.x & 63;
    const int wave = threadIdx.x >> 6;
    const int wrow = blockIdx.x * 128 + wave * 32;   // 32 rows per wave
    const int arow = lane & 31;       // A row / C col-class
    const int half = lane >> 5;       // A k-group / C row-half

    // ---- build A fragments (hi/lo), 4 k-steps ----
    // A layout (mirrors verified m120): A[row=lane&31][k=(lane>>5)*8+j]
    bf16x8 ah[4], al[4];
    {
        const float* xp = x + (size_t)(wrow + arow) * DDIM + half * 8;
#pragma unroll
        for (int s = 0; s < 4; ++s) {
            float4 v0 = *(const float4*)(xp + s * 16);
            float4 v1 = *(const float4*)(xp + s * 16 + 4);
            float f[8] = {v0.x, v0.y, v0.z, v0.w, v1.x, v1.y, v1.z, v1.w};
#pragma unroll
            for (int j = 0; j < 8; ++j) {
                unsigned short h = bf16_rne(f[j]);
                float hf = __uint_as_float((unsigned)h << 16);
                ah[s][j] = (short)h;
                al[s][j] = (short)bf16_rne(f[j] - hf);
            }
        }
    }

    // ---- per-lane running (min1, min2, argmin), 16 slots (C rows) ----
    float m1[16], m2[16];
    int   id[16];
#pragma unroll
    for (int r = 0; r < 16; ++r) { m1[r] = 3.4e38f; m2[r] = 3.4e38f; id[r] = 0; }

    const bf16x8* __restrict__ phv = (const bf16x8*)ph;
    const bf16x8* __restrict__ plv = (const bf16x8*)pl;

    // fragment index (bf16x8 units): (tile<<8) + (kstep<<6) + lane
    // ---- prologue: prefetch k0/k1 of tile 0 ----
    bf16x8 bh0 = phv[lane];
    bf16x8 bh1 = phv[64 + lane];
    bf16x8 bl0 = plv[lane];
    bf16x8 bl1 = plv[64 + lane];

    for (int tile = 0; tile < KCODE / 32; ++tile) {
        const int base = tile << 8;
        // issue k2/k3 loads of CURRENT tile; latency hides under k0/k1 MFMAs
        bf16x8 bh2 = phv[base + 128 + lane];
        bf16x8 bh3 = phv[base + 192 + lane];
        bf16x8 bl2 = plv[base + 128 + lane];
        bf16x8 bl3 = plv[base + 192 + lane];

        const int code = (tile << 5) | arow;          // this lane's C col
        const float nrm = norms[code];                // feeds epilogue only

        f32x16 acc = {0.f,0.f,0.f,0.f,0.f,0.f,0.f,0.f,
                      0.f,0.f,0.f,0.f,0.f,0.f,0.f,0.f};
        acc = __builtin_amdgcn_mfma_f32_32x32x16_bf16(ah[0], bh0, acc, 0, 0, 0);
        acc = __builtin_amdgcn_mfma_f32_32x32x16_bf16(ah[0], bl0, acc, 0, 0, 0);
        acc = __builtin_amdgcn_mfma_f32_32x32x16_bf16(al[0], bh0, acc, 0, 0, 0);
        acc = __builtin_amdgcn_mfma_f32_32x32x16_bf16(ah[1], bh1, acc, 0, 0, 0);
        acc = __builtin_amdgcn_mfma_f32_32x32x16_bf16(ah[1], bl1, acc, 0, 0, 0);
        acc = __builtin_amdgcn_mfma_f32_32x32x16_bf16(al[1], bh1, acc, 0, 0, 0);

        // ---- prefetch k0/k1 of NEXT tile while k2/k3 MFMAs run ----
        if (tile + 1 < KCODE / 32) {
            const int nb = base + 256;
            bh0 = phv[nb + lane];
            bh1 = phv[nb + 64 + lane];
            bl0 = plv[nb + lane];
            bl1 = plv[nb + 64 + lane];
        }

        acc = __builtin_amdgcn_mfma_f32_32x32x16_bf16(ah[2], bh2, acc, 0, 0, 0);
        acc = __builtin_amdgcn_mfma_f32_32x32x16_bf16(ah[2], bl2, acc, 0, 0, 0);
        acc = __builtin_amdgcn_mfma_f32_32x32x16_bf16(al[2], bh2, acc, 0, 0, 0);
        acc = __builtin_amdgcn_mfma_f32_32x32x16_bf16(ah[3], bh3, acc, 0, 0, 0);
        acc = __builtin_amdgcn_mfma_f32_32x32x16_bf16(ah[3], bl3, acc, 0, 0, 0);
        acc = __builtin_amdgcn_mfma_f32_32x32x16_bf16(al[3], bh3, acc, 0, 0, 0);

        // C layout (verified m74/m101): col=lane&31, row=(r&3)+8*(r>>2)+4*half
#pragma unroll
        for (int r = 0; r < 16; ++r) {
            float sv = fmaf(-2.0f, acc[r], nrm);
            // m2' = median(m1, m2, sv) == (sv<m1 ? m1 : min(m2,sv)) given m1<=m2
            m2[r] = __builtin_amdgcn_fmed3f(m1[r], m2[r], sv);
            bool lt = sv < m1[r];
            m1[r] = lt ? sv : m1[r];
            id[r] = lt ? code : id[r];
        }
    }

    // ---- cross-lane merge over the 32 code-columns (within each 32-lane half)
#pragma unroll
    for (int r = 0; r < 16; ++r) {
        float a1 = m1[r], a2 = m2[r];
        int   ai = id[r];
        for (int mask = 1; mask < 32; mask <<= 1) {
            float o1 = __shfl_xor(a1, mask, 64);
            float o2 = __shfl_xor(a2, mask, 64);
            int   oi = __shfl_xor(ai, mask, 64);
            float n2 = fminf(fminf(a2, o2), fmaxf(a1, o1));
            bool take = o1 < a1;
            a1 = take ? o1 : a1;
            ai = take ? oi : ai;
            a2 = n2;
        }
        m1[r] = a1; m2[r] = a2; id[r] = ai;
    }

    // After the merge, (m1,m2,id) are uniform across each 32-lane half, so
    // every lane computes its half's flag count (no divergence).
    int nf = 0;
#pragma unroll
    for (int r = 0; r < 16; ++r)
        nf += ((m2[r] - m1[r]) <= WINDOW) ? 1 : 0;

    // wave-aggregated worklist append: ONE atomic per wave
    int myoff = 0;
    if (list) {
        int nf0 = __shfl(nf, 0, 64);
        int nf1 = __shfl(nf, 32, 64);
        int wtotal = nf0 + nf1;
        int wbase = 0;
        if (lane == 0 && wtotal) wbase = atomicAdd(cnt, wtotal);
        wbase = __shfl(wbase, 0, 64);
        myoff = wbase + (half ? nf0 : 0);
    }

    if (arow == 0) {   // lanes 0 (half=0 rows) and 32 (half=1 rows) write
#pragma unroll
        for (int r = 0; r < 16; ++r) {
            int row = wrow + (r & 3) + 8 * (r >> 2) + 4 * half;
            bool flag = (m2[r] - m1[r]) <= WINDOW;
            idx[row] = flag ? (id[r] | 0x80000000) : id[r];
            if (list && flag) list[myoff++] = row;
        }
    }
}

// ------------------------------------------------------------------
// Rb: exact numpy rescore, one BLOCK per group of 4 worklist rows.
// Thread t owns codes k = 4t..4t+3 (ascending within thread; lexicographic
// (value,index) reduction across threads => global first-index argmin).
// Per d-step: one dwordx4 load of e[d][4t..4t+3] (wave reads a contiguous
// 1 KiB slice -> fully coalesced) + LDS broadcast of xs[r][d] + 16 chained
// FMAs (4 rows x 4 codes, independent chains -> issue-bound, latency hidden).
// Each chain's op order is IDENTICAL to vq_rescore: bit-exact.
__global__ __launch_bounds__(256) void vq_rescore_b(const float* __restrict__ x,
                                                    const float* __restrict__ e,   // [D][K]
                                                    const float* __restrict__ norms,
                                                    int* __restrict__ idx,
                                                    const int* __restrict__ cnt,
                                                    const int* __restrict__ list) {
#pragma clang fp contract(off)
    __shared__ float xs[4][DDIM];     // 4 staged rows
    __shared__ float sumxs[4];
    __shared__ int   rows_s[4];
    __shared__ float wval[4][4];      // [row][wave] lex-reduce partials
    __shared__ int   widx[4][4];

    const int tid  = threadIdx.x;
    const int lane = tid & 63;
    const int wave = tid >> 6;
    const int total = *cnt;
    const int ngroups = (total + 3) >> 2;

    const float* ep = e + (tid << 2);                       // e[0][4t]
    const float4 nv = *(const float4*)(norms + (tid << 2)); // norms[4t..4t+3]

    for (int g = blockIdx.x; g < ngroups; g += gridDim.x) {
        const int base = g * 4;
        const int nr = min(4, total - base);

        // ---- stage 4 rows into LDS (64 threads per row, stride-1: no conflicts)
        {
            int r = wave;            // tid>>6: one wave per row
            int d = lane;
            int row = (r < nr) ? list[base + r] : list[base];  // pad with row 0
            if (d == 0) rows_s[r] = row;
            xs[r][d] = x[(size_t)row * DDIM + d];
        }
        __syncthreads();

        // ---- sumsq per row: wave r computes row r with a bit-exact 16-lane tree.
        // u[j] on lane j (j<16); each xor level adds self+other, reproducing
        // numpy's pairwise order exactly (IEEE add is bitwise commutative).
        {
            int r = wave;
            float uj = 0.f;
            if (lane < 16) {
                float a0 = xs[r][lane];
                float a1 = xs[r][lane + 16];
                float a2 = xs[r][lane + 32];
                float a3 = xs[r][lane + 48];
                float p0 = a0 * a0, p1 = a1 * a1, p2 = a2 * a2, p3 = a3 * a3;
                uj = (p0 + p1) + (p2 + p3);
            }
            uj = uj + __shfl_xor(uj, 8, 64);   // v8[j] = u[j] + u[j+8]
            uj = uj + __shfl_xor(uj, 4, 64);   // w4[j] = v8[j] + v8[j+4]
            uj = uj + __shfl_xor(uj, 2, 64);   // y0 = w4[0]+w4[2] (lane0)
            uj = uj + __shfl_xor(uj, 1, 64);   // y0+y1 (lane0)
            if (lane == 0) sumxs[r] = uj;
        }
        __syncthreads();

        // ---- 16 independent sequential-d chains: 4 rows x 4 codes ----
        f32x4 a0 = {0.f, 0.f, 0.f, 0.f};
        f32x4 a1 = {0.f, 0.f, 0.f, 0.f};
        f32x4 a2 = {0.f, 0.f, 0.f, 0.f};
        f32x4 a3 = {0.f, 0.f, 0.f, 0.f};
#pragma unroll 8
        for (int d = 0; d < DDIM; ++d) {
            float4 ev = *(const float4*)(ep + (size_t)d * KCODE);
            float x0 = xs[0][d], x1 = xs[1][d], x2 = xs[2][d], x3 = xs[3][d];
            a0.x = fmaf(x0, ev.x, a0.x); a0.y = fmaf(x0, ev.y, a0.y);
            a0.z = fmaf(x0, ev.z, a0.z); a0.w = fmaf(x0, ev.w, a0.w);
            a1.x = fmaf(x1, ev.x, a1.x); a1.y = fmaf(x1, ev.y, a1.y);
            a1.z = fmaf(x1, ev.z, a1.z); a1.w = fmaf(x1, ev.w, a1.w);
            a2.x = fmaf(x2, ev.x, a2.x); a2.y = fmaf(x2, ev.y, a2.y);
            a2.z = fmaf(x2, ev.z, a2.z); a2.w = fmaf(x2, ev.w, a2.w);
            a3.x = fmaf(x3, ev.x, a3.x); a3.y = fmaf(x3, ev.y, a3.y);
            a3.z = fmaf(x3, ev.z, a3.z); a3.w = fmaf(x3, ev.w, a3.w);
        }

        // ---- per-row distances + lexicographic first-index argmin ----
#pragma unroll
        for (int r = 0; r < 4; ++r) {
            f32x4 ar = (r == 0) ? a0 : (r == 1) ? a1 : (r == 2) ? a2 : a3;
            float sx = sumxs[r];
            float bv = 3.4e38f; int bx = 0;
            {   // ascending k within thread: first-index on ties via strict <
                float t0 = sx + nv.x; float d0 = t0 - 2.0f * ar.x;
                if (d0 < bv) { bv = d0; bx = (tid << 2) + 0; }
                float t1 = sx + nv.y; float d1 = t1 - 2.0f * ar.y;
                if (d1 < bv) { bv = d1; bx = (tid << 2) + 1; }
                float t2 = sx + nv.z; float d2 = t2 - 2.0f * ar.z;
                if (d2 < bv) { bv = d2; bx = (tid << 2) + 2; }
                float t3 = sx + nv.w; float d3 = t3 - 2.0f * ar.w;
                if (d3 < bv) { bv = d3; bx = (tid << 2) + 3; }
            }
            for (int mask = 32; mask; mask >>= 1) {
                float ov = __shfl_xor(bv, mask, 64);
                int   ox = __shfl_xor(bx, mask, 64);
                if (ov < bv || (ov == bv && ox < bx)) { bv = ov; bx = ox; }
            }
            if (lane == 0) { wval[r][wave] = bv; widx[r][wave] = bx; }
        }
        __syncthreads();

        if (tid < nr) {
            float bv = wval[tid][0]; int bx = widx[tid][0];
#pragma unroll
            for (int w = 1; w < 4; ++w) {
                float ov = wval[tid][w]; int ox = widx[tid][w];
                if (ov < bv || (ov == bv && ox < bx)) { bv = ov; bx = ox; }
            }
            idx[rows_s[tid]] = bx;    // clears flag bit
        }
        __syncthreads();   // protect xs/rows_s/wval before next group
    }
}

// ------------------------------------------------------------------
// R (fallback, only if ws too small for the worklist): exact numpy rescore
// of flagged rows. One wave per row. UNCHANGED from verified version.
__global__ __launch_bounds__(256) void vq_rescore(const float* __restrict__ x,
                                                  const float* __restrict__ eT,
                                                  const float* __restrict__ norms,
                                                  int* __restrict__ idx) {
#pragma clang fp contract(off)
    const int wave = threadIdx.x >> 6;
    const int lane = threadIdx.x & 63;
    const int rowbase = blockIdx.x * 16 + wave * 4;   // 16384 blocks x 16 rows
    for (int i = 0; i < 4; ++i) {
        const int row = rowbase + i;
        if (idx[row] >= 0) continue;           // uniform branch (broadcast load)
        float xr[DDIM];
        const float4* xv = (const float4*)(x + (size_t)row * DDIM);
#pragma unroll
        for (int t = 0; t < DDIM / 4; ++t) {
            float4 v = xv[t];
            xr[4*t+0] = v.x; xr[4*t+1] = v.y; xr[4*t+2] = v.z; xr[4*t+3] = v.w;
        }
        float sumx = numpy_sumsq(xr);
        float best = 3.4e38f; int bi = 0;
        for (int j = 0; j < 16; ++j) {
            const int k = j * 64 + lane;       // ascending k per lane
            const float* __restrict__ ek = eT + (k << 6);
            float a = 0.f;
#pragma unroll
            for (int d = 0; d < DDIM; ++d)
                a = fmaf(xr[d], ek[d], a);     // strict sequential d-chain
            float t0 = sumx + norms[k];
            float dist = t0 - 2.0f * a;        // fl(fl(sumx+norm) - 2*dot)
            if (dist < best) { best = dist; bi = k; }
        }
        // lexicographic (value, index) min across 64 lanes = first-index argmin
        for (int mask = 32; mask; mask >>= 1) {
            float ov = __shfl_xor(best, mask, 64);
            int   oi = __shfl_xor(bi,   mask, 64);
            if (ov < best || (ov == best && oi < bi)) { best = ov; bi = oi; }
        }
        if (lane == 0) idx[row] = bi;          // clears flag bit
    }
}

// ------------------------------------------------------------------
// 2: gather + straight-through + per-BLOCK loss partial (UNCHANGED, verified)
__global__ __launch_bounds__(256) void vq_gather(const float* __restrict__ x,
                                                 const float* __restrict__ eT,
                                                 const int* __restrict__ idx,
                                                 float* __restrict__ out,
                                                 double* __restrict__ partials) {
#pragma clang fp contract(off)
    __shared__ float wsum[4];
    const int t   = blockIdx.x * 256 + threadIdx.x;   // NROWS*16 threads
    const int row = t >> 4;
    const int j   = t & 15;
    const int k   = idx[row];
    float4 q  = ((const float4*)eT)[(k << 4) + j];
    float4 xv = ((const float4*)x)[t];
    float dx = q.x - xv.x, dy = q.y - xv.y, dz = q.z - xv.z, dw = q.w - xv.w;
    float4 o;
    o.x = xv.x + dx; o.y = xv.y + dy; o.z = xv.z + dz; o.w = xv.w + dw;
    ((float4*)out)[t] = o;
    float s = dx*dx + dy*dy + dz*dz + dw*dw;
#pragma unroll
    for (int off = 32; off > 0; off >>= 1) s += __shfl_down(s, off, 64);
    if ((threadIdx.x & 63) == 0) wsum[threadIdx.x >> 6] = s;
    __syncthreads();
    if (threadIdx.x == 0) {
        double b = (double)wsum[0] + (double)wsum[1]
                 + (double)wsum[2] + (double)wsum[3];
        partials[blockIdx.x] = b;
    }
}

// ------------------------------------------------------------------
// 3: reduce block partials; loss = 1.25 * mse (UNCHANGED, verified)
__global__ __launch_bounds__(256) void vq_finalize(const double* __restrict__ partials,
                                                   float* __restrict__ out_loss) {
    __shared__ double sd[256];
    double a = 0.0;
    for (int i = threadIdx.x; i < GATHER_BLOCKS; i += 256) a += partials[i];
    sd[threadIdx.x] = a;
    __syncthreads();
    for (int s = 128; s > 0; s >>= 1) {
        if (threadIdx.x < s) sd[threadIdx.x] += sd[threadIdx.x + s];
        __syncthreads();
    }
    if (threadIdx.x == 0) {
        double mse = sd[0] / (double)((size_t)NROWS * DDIM);
        *out_loss = (float)(1.25 * mse);
    }
}

// ------------------------------------------------------------------
extern "C" void kernel_launch(void* const* d_in, const int* in_sizes, int n_in,
                              void* d_out, int out_size, void* d_ws, size_t ws_size,
                              hipStream_t stream) {
    const float* x = (const float*)d_in[0];        // [N, 64]
    const float* e = (const float*)d_in[1];        // [64, 1024]
    float* out = (float*)d_out;                    // [N*64 quantized_st] + [1 loss]

    char* ws = (char*)d_ws;
    float*          eT       = (float*)(ws + 0);
    float*          norms    = (float*)(ws + 262144);
    unsigned short* ph       = (unsigned short*)(ws + 266240);
    unsigned short* pl       = (unsigned short*)(ws + 397312);
    int*            idx      = (int*)(ws + 528384);
    double*         partials = (double*)(ws + 1576960);

    const size_t CNT_OFF  = 1708032;
    const size_t LIST_OFF = 1709056;
    const size_t REQUIRED = LIST_OFF + (size_t)NROWS * 4;   // ~2.63 MiB
    const bool compact = (ws_size >= REQUIRED);
    int* cnt  = compact ? (int*)(ws + CNT_OFF)  : (int*)0;
    int* list = compact ? (int*)(ws + LIST_OFF) : (int*)0;

    vq_prep    <<<KCODE / 256,   256, 0, stream>>>(e, eT, norms, ph, pl, cnt);
    vq_filter  <<<NROWS / 128,   256, 0, stream>>>(x, ph, pl, norms, idx, cnt, list);
    if (compact)
        vq_rescore_b<<<2048,     256, 0, stream>>>(x, e, norms, idx, cnt, list);
    else
        vq_rescore  <<<NROWS/16, 256, 0, stream>>>(x, eT, norms, idx);
    vq_gather  <<<GATHER_BLOCKS, 256, 0, stream>>>(x, eT, idx, out, partials);
    vq_finalize<<<1,             256, 0, stream>>>(partials, out + (size_t)NROWS * DDIM);
}